// Round 1
// baseline (333.992 us; speedup 1.0000x reference)
//
#include <hip/hip_runtime.h>

typedef __bf16 bf16;
typedef __bf16 bf16x8 __attribute__((ext_vector_type(8)));
typedef __bf16 bf16x4 __attribute__((ext_vector_type(4)));
typedef float f32x4 __attribute__((ext_vector_type(4)));

#define GLL16(gp, lp)                                                          \
  __builtin_amdgcn_global_load_lds(                                            \
      (const __attribute__((address_space(1))) unsigned int*)(gp),             \
      (__attribute__((address_space(3))) unsigned int*)(lp), 16, 0, 0)

// ---------------------------------------------------------------- cast fp32->bf16
__global__ __launch_bounds__(256) void cast_f32_bf16(
    const float* __restrict__ in, bf16* __restrict__ out, int n4) {
  int i = blockIdx.x * blockDim.x + threadIdx.x;
  int stride = gridDim.x * blockDim.x;
  for (; i < n4; i += stride) {
    float4 v = ((const float4*)in)[i];
    bf16x4 o;
    o[0] = (bf16)v.x; o[1] = (bf16)v.y; o[2] = (bf16)v.z; o[3] = (bf16)v.w;
    ((bf16x4*)out)[i] = o;
  }
}

// ---------------------------------------------------------------- GEMM C = A * B^T
// A: MxK bf16 row-major, B: NxK bf16 row-major, C: MxN fp32 (ldc = LDC).
// 128x128 tile, 4 waves (2x2 of 64x64), BK=64, global_load_lds staging,
// XOR-swizzled LDS (16B granules) so fragment ds_read_b128 is 2-way (free).
template <int K, int LDC>
__global__ __launch_bounds__(256) void gemm_bt(
    const bf16* __restrict__ A, const bf16* __restrict__ B,
    float* __restrict__ C) {
  __shared__ __align__(16) bf16 As[128 * 64];
  __shared__ __align__(16) bf16 Bs[128 * 64];
  const int tid  = threadIdx.x;
  const int lane = tid & 63;
  const int wave = tid >> 6;
  const int ln15 = lane & 15, quad = lane >> 4;
  const int wm = wave >> 1, wn = wave & 1;
  const int m0 = blockIdx.y * 128, n0 = blockIdx.x * 128;

  f32x4 acc[4][4] = {};

  for (int k0 = 0; k0 < K; k0 += 64) {
    __syncthreads();
#pragma unroll
    for (int j = 0; j < 4; ++j) {
      int gbase = j * 256 + wave * 64;        // wave-uniform granule base
      int g = gbase + lane;                   // per-lane granule
      int r = g >> 3, c = (g & 7) ^ (r & 7);  // swizzled column granule
      GLL16(A + (size_t)(m0 + r) * K + k0 + c * 8, As + (size_t)gbase * 8);
    }
#pragma unroll
    for (int j = 0; j < 4; ++j) {
      int gbase = j * 256 + wave * 64;
      int g = gbase + lane;
      int r = g >> 3, c = (g & 7) ^ (r & 7);
      GLL16(B + (size_t)(n0 + r) * K + k0 + c * 8, Bs + (size_t)gbase * 8);
    }
    __syncthreads();
#pragma unroll
    for (int kk = 0; kk < 2; ++kk) {
      bf16x8 af[4], bfr[4];
#pragma unroll
      for (int mi = 0; mi < 4; ++mi) {
        int m = wm * 64 + mi * 16 + ln15;
        int cg = kk * 4 + quad;
        af[mi] = *(const bf16x8*)(As + (m * 8 + (cg ^ (m & 7))) * 8);
      }
#pragma unroll
      for (int ni = 0; ni < 4; ++ni) {
        int n = wn * 64 + ni * 16 + ln15;
        int cg = kk * 4 + quad;
        bfr[ni] = *(const bf16x8*)(Bs + (n * 8 + (cg ^ (n & 7))) * 8);
      }
#pragma unroll
      for (int mi = 0; mi < 4; ++mi)
#pragma unroll
        for (int ni = 0; ni < 4; ++ni)
          acc[mi][ni] = __builtin_amdgcn_mfma_f32_16x16x32_bf16(
              af[mi], bfr[ni], acc[mi][ni], 0, 0, 0);
    }
  }
#pragma unroll
  for (int mi = 0; mi < 4; ++mi)
#pragma unroll
    for (int ni = 0; ni < 4; ++ni)
#pragma unroll
      for (int r = 0; r < 4; ++r) {
        int row = m0 + wm * 64 + mi * 16 + quad * 4 + r;  // C/D: row=(lane>>4)*4+reg
        int col = n0 + wn * 64 + ni * 16 + ln15;          //      col=lane&15
        C[(size_t)row * LDC + col] = acc[mi][ni][r];
      }
}

// ---------------------------------------------------------------- qkv epilogue
// Per (head, 64 t's): RMSNorm+rotary on q,k -> bf16 qn,kn [T][1024];
// v = l0*v + l1*ve transposed -> bf16 vt [H][128][T].
__global__ __launch_bounds__(256) void qkv_post(
    const float* __restrict__ qkv, const float* __restrict__ ve,
    const float* __restrict__ lambdas, bf16* __restrict__ qn,
    bf16* __restrict__ kn, bf16* __restrict__ vt) {
  const int h  = blockIdx.x;       // 0..7
  const int t0 = blockIdx.y * 64;  // 64 rows per block
  const int tid = threadIdx.x;
  const int wave = tid >> 6, lane = tid & 63;
  __shared__ __align__(16) float tile[64][129];  // +1 pad: conflict-free transpose

  // Phase A: q/k rms+rotary. Lane j holds the rotary pair (d=j, d=j+64).
  const int j = lane;
  float cth = 1.0f, sth = 0.0f;
  for (int i = 0; i < 16; ++i) {
    int t = t0 + wave * 16 + i;
    if (j < 32) {
      float ang = exp2f((float)j * (-10.0f / 31.0f));  // (1/1024)^(j/31)
      float th = (float)t * ang;
      sincosf(th, &sth, &cth);
    }
#pragma unroll
    for (int qk = 0; qk < 2; ++qk) {
      const float* row = qkv + (size_t)t * 3072 + qk * 1024 + h * 128;
      float x1 = row[j], x2 = row[j + 64];
      float ss = x1 * x1 + x2 * x2;
#pragma unroll
      for (int m = 1; m < 64; m <<= 1) ss += __shfl_xor(ss, m, 64);
      float rinv = rsqrtf(ss * (1.0f / 128.0f) + 1.1920929e-7f);
      float y1 = (x1 * cth + x2 * sth) * rinv;
      float y2 = (x2 * cth - x1 * sth) * rinv;
      bf16* orow = (qk == 0 ? qn : kn) + (size_t)t * 1024 + h * 128;
      orow[j] = (bf16)y1;
      orow[j + 64] = (bf16)y2;
    }
  }

  // Phase B: v merge + transpose through LDS.
  float l0 = lambdas[0], l1 = lambdas[1];
  for (int c = 0; c < 32; ++c) {
    int idx = c * 256 + tid;
    int d = idx & 127, tl = idx >> 7;
    int t = t0 + tl;
    float v = qkv[(size_t)t * 3072 + 2048 + h * 128 + d];
    float vev = ve[(size_t)t * 1024 + h * 128 + d];
    tile[tl][d] = l0 * v + l1 * vev;
  }
  __syncthreads();
  for (int c = 0; c < 32; ++c) {
    int idx = c * 256 + tid;
    int tl = idx & 63, d = idx >> 6;
    vt[((size_t)(h * 128 + d)) * 4096 + t0 + tl] = (bf16)tile[tl][d];
  }
}

// ---------------------------------------------------------------- flash attention
// BM=BN=64, Hd=128. 4 waves, each owns 16 q-rows (full 64 kv cols / 128 d cols).
// Block processes q-tiles p and 63-p (equal causal work: 65 kv-iters per block).
__global__ __launch_bounds__(256) void flash_attn(
    const bf16* __restrict__ qn, const bf16* __restrict__ kn,
    const bf16* __restrict__ vt, bf16* __restrict__ y) {
  const int h = blockIdx.x & 7;          // %8: same-head blocks share XCD L2
  const int pairIdx = blockIdx.x >> 3;   // 0..31
  const int tid = threadIdx.x;
  const int wave = tid >> 6, lane = tid & 63;
  const int ln15 = lane & 15, quad = lane >> 4;

  __shared__ __align__(16) bf16 Ks[64 * 128];      // [kv][d], 16-gran swizzle
  __shared__ __align__(16) bf16 Vs[128 * 64];      // [d][kv], 8-gran swizzle
  __shared__ __align__(16) bf16 Ps[4 * 16 * 64];   // per-wave P, 8-gran swizzle
  bf16* Pw = Ps + wave * 16 * 64;

  for (int half = 0; half < 2; ++half) {
    const int qtile = (half == 0) ? pairIdx : (63 - pairIdx);
    const int q0 = qtile * 64;

    // Q fragments (A-layout: m=lane&15, k=quad*8+j) straight from global.
    bf16x8 qf[4];
    {
      const bf16* qb =
          qn + (size_t)(q0 + wave * 16 + ln15) * 1024 + h * 128 + quad * 8;
#pragma unroll
      for (int ks = 0; ks < 4; ++ks) qf[ks] = *(const bf16x8*)(qb + ks * 32);
    }
    float m_i[4], l_i[4];
    f32x4 acc_o[8] = {};
#pragma unroll
    for (int r = 0; r < 4; ++r) { m_i[r] = -__builtin_inff(); l_i[r] = 0.0f; }

    const int nkv = qtile + 1;
    for (int kt = 0; kt < nkv; ++kt) {
      const int kv0 = kt * 64;
      __syncthreads();  // previous tile's LDS reads done
#pragma unroll
      for (int jj = 0; jj < 4; ++jj) {  // K tile: 64 rows x 16 granules
        int gbase = jj * 256 + wave * 64;
        int g = gbase + lane;
        int r = g >> 4, c = (g & 15) ^ (r & 15);
        GLL16(kn + (size_t)(kv0 + r) * 1024 + h * 128 + c * 8,
              Ks + (size_t)gbase * 8);
      }
#pragma unroll
      for (int jj = 0; jj < 4; ++jj) {  // V^T tile: 128 rows x 8 granules
        int gbase = jj * 256 + wave * 64;
        int g = gbase + lane;
        int d = g >> 3, c = (g & 7) ^ (d & 7);
        GLL16(vt + ((size_t)(h * 128 + d)) * 4096 + kv0 + c * 8,
              Vs + (size_t)gbase * 8);
      }
      __syncthreads();

      // S = Q K^T (this wave's 16 rows x 64 cols)
      f32x4 accs[4] = {};
#pragma unroll
      for (int ks = 0; ks < 4; ++ks)
#pragma unroll
        for (int nf = 0; nf < 4; ++nf) {
          int n = nf * 16 + ln15;
          bf16x8 b =
              *(const bf16x8*)(Ks + (n * 16 + ((ks * 4 + quad) ^ ln15)) * 8);
          accs[nf] =
              __builtin_amdgcn_mfma_f32_16x16x32_bf16(qf[ks], b, accs[nf], 0, 0, 0);
        }

      // online softmax (rows quad*4+r, shared by the quad's 16 lanes)
      float sv[4][4], mx[4];
#pragma unroll
      for (int r = 0; r < 4; ++r) mx[r] = -__builtin_inff();
      const bool diag = (kt == nkv - 1);
#pragma unroll
      for (int nf = 0; nf < 4; ++nf)
#pragma unroll
        for (int r = 0; r < 4; ++r) {
          float s = accs[nf][r] * 0.12f;
          if (diag && (nf * 16 + ln15 > wave * 16 + quad * 4 + r))
            s = -__builtin_inff();
          sv[nf][r] = s;
          mx[r] = fmaxf(mx[r], s);
        }
#pragma unroll
      for (int m = 1; m < 16; m <<= 1)
#pragma unroll
        for (int r = 0; r < 4; ++r) mx[r] = fmaxf(mx[r], __shfl_xor(mx[r], m, 64));
      float alpha[4], rs[4];
#pragma unroll
      for (int r = 0; r < 4; ++r) {
        float mn = fmaxf(m_i[r], mx[r]);
        alpha[r] = __expf(m_i[r] - mn);
        m_i[r] = mn;
        rs[r] = 0.0f;
      }
#pragma unroll
      for (int nf = 0; nf < 4; ++nf)
#pragma unroll
        for (int r = 0; r < 4; ++r) {
          float p = __expf(sv[nf][r] - m_i[r]);
          rs[r] += p;
          int mr = quad * 4 + r, n = nf * 16 + ln15;
          Pw[(mr * 8 + ((n >> 3) ^ (mr & 7))) * 8 + (n & 7)] = (bf16)p;
        }
#pragma unroll
      for (int m = 1; m < 16; m <<= 1)
#pragma unroll
        for (int r = 0; r < 4; ++r) rs[r] += __shfl_xor(rs[r], m, 64);
#pragma unroll
      for (int r = 0; r < 4; ++r) l_i[r] = l_i[r] * alpha[r] + rs[r];
#pragma unroll
      for (int nf = 0; nf < 8; ++nf)
#pragma unroll
        for (int r = 0; r < 4; ++r) acc_o[nf][r] *= alpha[r];

      // O += P V  (P via LDS round-trip into A-layout; V^T gives B-layout)
#pragma unroll
      for (int ks2 = 0; ks2 < 2; ++ks2) {
        bf16x8 a =
            *(const bf16x8*)(Pw + (ln15 * 8 + ((ks2 * 4 + quad) ^ (ln15 & 7))) * 8);
#pragma unroll
        for (int nf2 = 0; nf2 < 8; ++nf2) {
          int d = nf2 * 16 + ln15;
          bf16x8 b =
              *(const bf16x8*)(Vs + (d * 8 + ((ks2 * 4 + quad) ^ (d & 7))) * 8);
          acc_o[nf2] =
              __builtin_amdgcn_mfma_f32_16x16x32_bf16(a, b, acc_o[nf2], 0, 0, 0);
        }
      }
    }
    // epilogue: y = O / l
#pragma unroll
    for (int nf2 = 0; nf2 < 8; ++nf2)
#pragma unroll
      for (int r = 0; r < 4; ++r) {
        int t = q0 + wave * 16 + quad * 4 + r;
        int col = nf2 * 16 + ln15;
        y[(size_t)t * 1024 + h * 128 + col] = (bf16)(acc_o[nf2][r] / l_i[r]);
      }
  }
}

// ---------------------------------------------------------------- launch
extern "C" void kernel_launch(void* const* d_in, const int* in_sizes, int n_in,
                              void* d_out, int out_size, void* d_ws,
                              size_t ws_size, hipStream_t stream) {
  const float* x       = (const float*)d_in[0];  // [1,4096,1024]
  const float* ve      = (const float*)d_in[1];  // [1,4096,1024]
  const float* qkv_w   = (const float*)d_in[2];  // [3,1024,1024]
  const float* lambdas = (const float*)d_in[3];  // [2]
  const float* c_proj  = (const float*)d_in[4];  // [1024,1024]
  float* out = (float*)d_out;                    // [1,4096,1024] fp32

  char* ws = (char*)d_ws;
  float* qkv  = (float*)ws;                   // 4096*3072 f32 = 48 MiB
  bf16* xbf   = (bf16*)(ws + 50331648);       // 8 MiB
  bf16* wqkv  = (bf16*)(ws + 58720256);       // 6 MiB
  bf16* wproj = (bf16*)(ws + 65011712);       // 2 MiB
  bf16* qn    = (bf16*)(ws + 67108864);       // 8 MiB
  bf16* kn    = (bf16*)(ws + 75497472);       // 8 MiB
  bf16* vt    = (bf16*)(ws + 83886080);       // 8 MiB  [H][128][T]
  bf16* yb    = (bf16*)(ws + 92274688);       // 8 MiB  (total ~96 MiB)

  cast_f32_bf16<<<1024, 256, 0, stream>>>(x, xbf, 4194304 / 4);
  cast_f32_bf16<<<1024, 256, 0, stream>>>(qkv_w, wqkv, 3145728 / 4);
  cast_f32_bf16<<<512, 256, 0, stream>>>(c_proj, wproj, 1048576 / 4);

  gemm_bt<1024, 3072><<<dim3(24, 32), 256, 0, stream>>>(xbf, wqkv, qkv);

  qkv_post<<<dim3(8, 64), 256, 0, stream>>>(qkv, ve, lambdas, qn, kn, vt);

  flash_attn<<<256, 256, 0, stream>>>(qn, kn, vt, yb);

  gemm_bt<1024, 1024><<<dim3(8, 32), 256, 0, stream>>>(yb, wproj, out);
}